// Round 5
// baseline (763.796 us; speedup 1.0000x reference)
//
#include <hip/hip_runtime.h>
#include <hip/hip_bf16.h>
#include <cstdint>
#include <cstddef>

typedef unsigned short u16;
typedef __bf16 bf16x8 __attribute__((ext_vector_type(8)));
typedef float f32x4 __attribute__((ext_vector_type(4)));

#define GLOBAL_AS(p) ((const __attribute__((address_space(1))) void*)(p))
#define LDS_AS(p)    ((__attribute__((address_space(3))) void*)(p))

__device__ __forceinline__ float b2f(u16 u) {
  return __builtin_bit_cast(float, (unsigned)u << 16);
}
__device__ __forceinline__ u16 f2b(float f) {
  unsigned u = __builtin_bit_cast(unsigned, f);
  u += 0x7FFFu + ((u >> 16) & 1u);   // round-to-nearest-even
  return (u16)(u >> 16);
}

// ---------------- f32 -> bf16 convert (4 elems/thread) ----------------
__global__ __launch_bounds__(256) void cvt_kernel(const float* __restrict__ src,
                                                  u16* __restrict__ dst, int n4) {
  int i = blockIdx.x * 256 + threadIdx.x;
  if (i < n4) {
    float4 f = ((const float4*)src)[i];
    ushort4 o;
    o.x = f2b(f.x); o.y = f2b(f.y); o.z = f2b(f.z); o.w = f2b(f.w);
    ((ushort4*)dst)[i] = o;
  }
}

// ---------------- 256x256 GEMM, BK=64, 8 waves; 8-phase schedule (T2+T3+T4+T5+T1) ----
// C(bf16, MxN) = A(bf16, MxK) @ W(bf16, NxK)^T + bias [+bias2] [gelu]
// LDS per buffer (32768 u16): A plane0 [256][32] | A plane1 | B plane0 | B plane1
//   (plane = K-half of the BK=64 tile; each plane is one DMA-linear 16 KiB half-tile)
// Swizzle: LDS[row][c4] holds Data[row][c4 ^ ((row>>1)&3)] (16B blocks); DMA source
//   pre-swizzled, ds_read applies same XOR (involution, rule #21).
// Per K-tile: 4 phases (kk x n-pair), each {ds_reads | stage 1 half-tile} barrier
//   {16 MFMA, setprio} barrier. Counted vmcnt(6) once per tile: stages run
//   {kt+1 B1 @ph0, kt+2 A0 @ph1, kt+2 B0 @ph2, kt+2 A1 @ph3}; every overwrite is
//   >=1 barrier after the last read of the old tile's plane; vmcnt(6) leaves the
//   3 kt+2 half-stages in flight while guaranteeing all of kt+1 landed.
template<int EPI>  // 0 = none, 1 = exact gelu
__global__ __launch_bounds__(512, 2)
void gemm256(const u16* __restrict__ A, const u16* __restrict__ W,
             const float* __restrict__ bias, const float* __restrict__ bias2,
             u16* __restrict__ C, int N, int K, int nTn)
{
  __shared__ alignas(16) u16 LDS[69632];   // 136 KiB (main loop 128 KiB + epi overlay)
  const int tid  = threadIdx.x;
  const int lane = tid & 63;
  const int wave = tid >> 6;

  // T1: XCD-chunked bijective swizzle (gridDim.x % 8 == 0 for all our shapes)
  const int bqc = (int)gridDim.x >> 3;
  const int t  = ((int)blockIdx.x & 7) * bqc + ((int)blockIdx.x >> 3);
  const int bm = t / nTn, bn = t % nTn;
  const size_t row0 = (size_t)bm << 8;
  const int col0 = bn << 8;

  // ---- staging geometry: half-tile = plane (256 rows x 32 cols, 16 KiB), 2 DMA/thread
  // round i covers rows i*128..i*128+127; thread: row sr = tid>>2, dest c4 = tid&3.
  // dest linear: wave-uniform base + lane*16B; source col pre-swizzled.
  const int sr  = tid >> 2;
  const int c4s = (tid & 3) ^ ((tid >> 3) & 3);
  const u16* gA = A + ((size_t)row0 + sr) * K + c4s * 8;
  const u16* gB = W + ((size_t)col0 + sr) * K + c4s * 8;
  const size_t rK = (size_t)128 * K;
  const int stW = wave * 512;              // wave-uniform dest offset within plane

  // ---- fragment read geometry
  const int wm = wave >> 2, wn = wave & 3;
  const int fr = lane & 15, kq = lane >> 4;
  const int c4r = (kq ^ ((fr >> 1) & 3)) * 8;          // swizzled 16B block
  const int aBase = (wm * 128 + fr) * 32 + c4r;        // within A plane
  const int bBase = 16384 + (wn * 64 + fr) * 32 + c4r; // within buffer (B plane0)

  auto STG = [&](const u16* g, int koff, u16* d) {
    __builtin_amdgcn_global_load_lds(GLOBAL_AS(g + koff), LDS_AS(d), 16, 0, 0);
    __builtin_amdgcn_global_load_lds(GLOBAL_AS(g + rK + koff), LDS_AS(d + 4096), 16, 0, 0);
  };

  f32x4 acc[8][4];
  {
    f32x4 z = {0.f, 0.f, 0.f, 0.f};
#pragma unroll
    for (int m = 0; m < 8; ++m)
#pragma unroll
      for (int n = 0; n < 4; ++n) acc[m][n] = z;
  }

  const int NT = K >> 6;   // NT >= 16 for all our shapes

  // prologue: t0 all 4 halves + t1 {A0,B0,A1} (7 half-stages, 14 loads)
  {
    u16* L0 = LDS;  u16* L1 = LDS + 32768;
    STG(gA, 0,  L0 + stW);              // t0 A0
    STG(gB, 0,  L0 + 16384 + stW);      // t0 B0
    STG(gA, 32, L0 + 8192  + stW);      // t0 A1
    STG(gB, 32, L0 + 24576 + stW);      // t0 B1
    STG(gA, 64, L1 + stW);              // t1 A0
    STG(gB, 64, L1 + 16384 + stW);      // t1 B0
    STG(gA, 96, L1 + 8192  + stW);      // t1 A1
    asm volatile("s_waitcnt vmcnt(6)" ::: "memory");   // t0 landed; t1 in flight
    __builtin_amdgcn_s_barrier();
  }

  bf16x8 af[8];
  for (int kt = 0; kt < NT; ++kt) {
    const u16* Lb = LDS + (kt & 1) * 32768;
    u16* Ln = LDS + ((kt + 1) & 1) * 32768;   // dest for kt+1 stages
    u16* Lc = LDS + (kt & 1) * 32768;         // dest for kt+2 stages (current buf)
    const int k1 = (kt + 1) << 6, k2 = (kt + 2) << 6;
    bf16x8 b0, b1, b2, b3;

    // ---- phase 0: kk=0, n in {0,1}; stage (kt+1) B1 ----
#pragma unroll
    for (int m = 0; m < 8; ++m) af[m] = *(const bf16x8*)(Lb + aBase + m * 512);
    b0 = *(const bf16x8*)(Lb + bBase);
    b1 = *(const bf16x8*)(Lb + bBase + 512);
    if (kt + 1 < NT) STG(gB, k1 + 32, Ln + 24576 + stW);
    __builtin_amdgcn_s_barrier();
    __builtin_amdgcn_s_setprio(1);
#pragma unroll
    for (int m = 0; m < 8; ++m) {
      acc[m][0] = __builtin_amdgcn_mfma_f32_16x16x32_bf16(af[m], b0, acc[m][0], 0, 0, 0);
      acc[m][1] = __builtin_amdgcn_mfma_f32_16x16x32_bf16(af[m], b1, acc[m][1], 0, 0, 0);
    }
    __builtin_amdgcn_s_setprio(0);
    __builtin_amdgcn_s_barrier();

    // ---- phase 1: kk=0, n in {2,3}; stage (kt+2) A0 ----
    b2 = *(const bf16x8*)(Lb + bBase + 1024);
    b3 = *(const bf16x8*)(Lb + bBase + 1536);
    if (kt + 2 < NT) STG(gA, k2, Lc + stW);
    __builtin_amdgcn_s_barrier();
    __builtin_amdgcn_s_setprio(1);
#pragma unroll
    for (int m = 0; m < 8; ++m) {
      acc[m][2] = __builtin_amdgcn_mfma_f32_16x16x32_bf16(af[m], b2, acc[m][2], 0, 0, 0);
      acc[m][3] = __builtin_amdgcn_mfma_f32_16x16x32_bf16(af[m], b3, acc[m][3], 0, 0, 0);
    }
    __builtin_amdgcn_s_setprio(0);
    __builtin_amdgcn_s_barrier();

    // ---- phase 2: kk=1, n in {0,1}; stage (kt+2) B0 ----
#pragma unroll
    for (int m = 0; m < 8; ++m) af[m] = *(const bf16x8*)(Lb + 8192 + aBase + m * 512);
    b0 = *(const bf16x8*)(Lb + 8192 + bBase);
    b1 = *(const bf16x8*)(Lb + 8192 + bBase + 512);
    if (kt + 2 < NT) STG(gB, k2, Lc + 16384 + stW);
    __builtin_amdgcn_s_barrier();
    __builtin_amdgcn_s_setprio(1);
#pragma unroll
    for (int m = 0; m < 8; ++m) {
      acc[m][0] = __builtin_amdgcn_mfma_f32_16x16x32_bf16(af[m], b0, acc[m][0], 0, 0, 0);
      acc[m][1] = __builtin_amdgcn_mfma_f32_16x16x32_bf16(af[m], b1, acc[m][1], 0, 0, 0);
    }
    __builtin_amdgcn_s_setprio(0);
    __builtin_amdgcn_s_barrier();

    // ---- phase 3: kk=1, n in {2,3}; stage (kt+2) A1; counted boundary wait ----
    b2 = *(const bf16x8*)(Lb + 8192 + bBase + 1024);
    b3 = *(const bf16x8*)(Lb + 8192 + bBase + 1536);
    if (kt + 2 < NT) STG(gA, k2 + 32, Lc + 8192 + stW);
    __builtin_amdgcn_s_barrier();
    __builtin_amdgcn_s_setprio(1);
#pragma unroll
    for (int m = 0; m < 8; ++m) {
      acc[m][2] = __builtin_amdgcn_mfma_f32_16x16x32_bf16(af[m], b2, acc[m][2], 0, 0, 0);
      acc[m][3] = __builtin_amdgcn_mfma_f32_16x16x32_bf16(af[m], b3, acc[m][3], 0, 0, 0);
    }
    __builtin_amdgcn_s_setprio(0);
    if (kt + 2 < NT) asm volatile("s_waitcnt vmcnt(6)" ::: "memory");
    else             asm volatile("s_waitcnt vmcnt(0)" ::: "memory");
    __builtin_amdgcn_s_barrier();
  }

  // ---- epilogue: wave-private LDS transpose -> coalesced 16B stores ----
  u16* Wl = LDS + wave * 8704;                 // 128 x 68 u16 (pad breaks kq-bank overlap)
  const int orow = kq << 2;
#pragma unroll
  for (int n = 0; n < 4; ++n) {
    const int gcol = col0 + wn * 64 + n * 16 + fr;
    float bb = 0.f;
    if (bias)  bb += bias[gcol];
    if (bias2) bb += bias2[gcol];
#pragma unroll
    for (int m = 0; m < 8; ++m) {
#pragma unroll
      for (int r = 0; r < 4; ++r) {
        float v = acc[m][n][r] + bb;
        if (EPI == 1) v = 0.5f * v * (1.f + erff(v * 0.70710678118654752f));
        Wl[(m * 16 + orow + r) * 68 + n * 16 + fr] = f2b(v);
      }
    }
  }
  asm volatile("s_waitcnt lgkmcnt(0)" ::: "memory");   // wave-private: no barrier needed
#pragma unroll
  for (int p = 0; p < 16; ++p) {
    const int row = p * 8 + (lane >> 3);
    const int cu  = (lane & 7) << 3;
    bf16x8 v = *(const bf16x8*)(Wl + row * 68 + cu);
    *(bf16x8*)(&C[(row0 + wm * 128 + row) * N + col0 + wn * 64 + cu]) = v;
  }
}

// ---------------- LayerNorm of residual sum: O = LN(X + Y) * g + b, row width 1024 ----
__global__ __launch_bounds__(256)
void ln_res(const u16* __restrict__ X, const u16* __restrict__ Y,
            const float* __restrict__ g, const float* __restrict__ bta,
            u16* __restrict__ O)
{
  const int row = blockIdx.x;
  const int tid = threadIdx.x;
  const size_t base = (size_t)row * 1024 + tid * 4;
  ushort4 xv = *(const ushort4*)(X + base);
  ushort4 yv = *(const ushort4*)(Y + base);
  float v0 = b2f(xv.x) + b2f(yv.x);
  float v1 = b2f(xv.y) + b2f(yv.y);
  float v2 = b2f(xv.z) + b2f(yv.z);
  float v3 = b2f(xv.w) + b2f(yv.w);
  float s  = v0 + v1 + v2 + v3;
  float ss = v0*v0 + v1*v1 + v2*v2 + v3*v3;
#pragma unroll
  for (int off = 32; off; off >>= 1) {
    s  += __shfl_down(s, off);
    ss += __shfl_down(ss, off);
  }
  __shared__ float red[8];
  if ((tid & 63) == 0) { red[tid >> 6] = s; red[4 + (tid >> 6)] = ss; }
  __syncthreads();
  const float S  = red[0] + red[1] + red[2] + red[3];
  const float SS = red[4] + red[5] + red[6] + red[7];
  const float mu  = S * (1.f / 1024.f);
  const float inv = rsqrtf(SS * (1.f / 1024.f) - mu * mu + 1e-5f);
  const int n = tid * 4;
  float4 gv = *(const float4*)(g + n);
  float4 bv = *(const float4*)(bta + n);
  ushort4 o;
  o.x = f2b((v0 - mu) * inv * gv.x + bv.x);
  o.y = f2b((v1 - mu) * inv * gv.y + bv.y);
  o.z = f2b((v2 - mu) * inv * gv.z + bv.z);
  o.w = f2b((v3 - mu) * inv * gv.w + bv.w);
  *(ushort4*)(O + base) = o;
}

// ---------------- 2-key attention combine, 8 heads of d=128 (strided inputs) ----------------
__global__ __launch_bounds__(256)
void attn2(const u16* __restrict__ Q, const u16* __restrict__ K0, const u16* __restrict__ V0, int sQ,
           const u16* __restrict__ K1, const u16* __restrict__ V1, int sK,
           u16* __restrict__ O)
{
  const int row = blockIdx.x;
  const int tid = threadIdx.x;
  const size_t bq = (size_t)row * sQ + tid * 4;
  const size_t bk = (size_t)row * sK + tid * 4;
  const size_t bo = (size_t)row * 1024 + tid * 4;
  ushort4 qv  = *(const ushort4*)(Q  + bq);
  ushort4 k0v = *(const ushort4*)(K0 + bq);
  ushort4 v0v = *(const ushort4*)(V0 + bq);
  ushort4 k1v = *(const ushort4*)(K1 + bk);
  ushort4 v1v = *(const ushort4*)(V1 + bk);
  float q0 = b2f(qv.x), q1 = b2f(qv.y), q2 = b2f(qv.z), q3 = b2f(qv.w);
  float d0 = q0*b2f(k0v.x) + q1*b2f(k0v.y) + q2*b2f(k0v.z) + q3*b2f(k0v.w);
  float d1 = q0*b2f(k1v.x) + q1*b2f(k1v.y) + q2*b2f(k1v.z) + q3*b2f(k1v.w);
#pragma unroll
  for (int off = 16; off; off >>= 1) {
    d0 += __shfl_xor(d0, off);
    d1 += __shfl_xor(d1, off);
  }
  const float sc = 0.088388347648318447f;  // 1/sqrt(128)
  float s0 = d0 * sc, s1 = d1 * sc;
  float mx = fmaxf(s0, s1);
  float e0 = expf(s0 - mx), e1 = expf(s1 - mx);
  float r = 1.f / (e0 + e1);
  float a0 = e0 * r, a1 = e1 * r;
  ushort4 o;
  o.x = f2b(a0 * b2f(v0v.x) + a1 * b2f(v1v.x));
  o.y = f2b(a0 * b2f(v0v.y) + a1 * b2f(v1v.y));
  o.z = f2b(a0 * b2f(v0v.z) + a1 * b2f(v1v.z));
  o.w = f2b(a0 * b2f(v0v.w) + a1 * b2f(v1v.w));
  *(ushort4*)(O + bo) = o;
}

// ---------------- final: out[row] = dot(LN(X + Y)*g + b, Wc) + bc ----------------
__global__ __launch_bounds__(256)
void final_k(const u16* __restrict__ X, const u16* __restrict__ Y,
             const float* __restrict__ g, const float* __restrict__ bta,
             const float* __restrict__ Wc, const float* __restrict__ bc,
             float* __restrict__ out)
{
  const int row = blockIdx.x;
  const int tid = threadIdx.x;
  const size_t base = (size_t)row * 1024 + tid * 4;
  ushort4 xv = *(const ushort4*)(X + base);
  ushort4 yv = *(const ushort4*)(Y + base);
  float v0 = b2f(xv.x) + b2f(yv.x);
  float v1 = b2f(xv.y) + b2f(yv.y);
  float v2 = b2f(xv.z) + b2f(yv.z);
  float v3 = b2f(xv.w) + b2f(yv.w);
  float s  = v0 + v1 + v2 + v3;
  float ss = v0*v0 + v1*v1 + v2*v2 + v3*v3;
#pragma unroll
  for (int off = 32; off; off >>= 1) {
    s  += __shfl_down(s, off);
    ss += __shfl_down(ss, off);
  }
  __shared__ float red[8];
  __shared__ float red2[4];
  if ((tid & 63) == 0) { red[tid >> 6] = s; red[4 + (tid >> 6)] = ss; }
  __syncthreads();
  const float S  = red[0] + red[1] + red[2] + red[3];
  const float SS = red[4] + red[5] + red[6] + red[7];
  const float mu  = S * (1.f / 1024.f);
  const float inv = rsqrtf(SS * (1.f / 1024.f) - mu * mu + 1e-5f);
  const int n = tid * 4;
  float4 gv = *(const float4*)(g + n);
  float4 bv = *(const float4*)(bta + n);
  float4 wv = *(const float4*)(Wc + n);
  float dot = ((v0 - mu) * inv * gv.x + bv.x) * wv.x
            + ((v1 - mu) * inv * gv.y + bv.y) * wv.y
            + ((v2 - mu) * inv * gv.z + bv.z) * wv.z
            + ((v3 - mu) * inv * gv.w + bv.w) * wv.w;
#pragma unroll
  for (int off = 32; off; off >>= 1) dot += __shfl_down(dot, off);
  if ((tid & 63) == 0) red2[tid >> 6] = dot;
  __syncthreads();
  if (tid == 0) out[row] = red2[0] + red2[1] + red2[2] + red2[3] + bc[0];
}

// =====================================================================
extern "C" void kernel_launch(void* const* d_in, const int* in_sizes, int n_in,
                              void* d_out, int out_size, void* d_ws, size_t ws_size,
                              hipStream_t stream) {
  const float* spatial = (const float*)d_in[0];
  const float* freq    = (const float*)d_in[1];
  const float* Wps   = (const float*)d_in[2];
  const float* bps   = (const float*)d_in[3];
  const float* Wpf   = (const float*)d_in[4];
  const float* bpf   = (const float*)d_in[5];
  // d_in[8], d_in[9], d_in[11], d_in[12] (ca_Wq/ca_Wk/ca_bq/ca_bk) are dead: softmax over 1 key == 1
  const float* pos_s = (const float*)d_in[6];
  const float* pos_f = (const float*)d_in[7];
  const float* ca_Wv = (const float*)d_in[10];
  const float* ca_bv = (const float*)d_in[13];
  const float* ca_Wo = (const float*)d_in[14];
  const float* ca_bo = (const float*)d_in[15];
  const float* n1_g  = (const float*)d_in[16];
  const float* n1_b  = (const float*)d_in[17];
  const float* W1    = (const float*)d_in[18];
  const float* b1    = (const float*)d_in[19];
  const float* W2    = (const float*)d_in[20];
  const float* b2    = (const float*)d_in[21];
  const float* n2_g  = (const float*)d_in[22];
  const float* n2_b  = (const float*)d_in[23];
  const float* sWq   = (const float*)d_in[24];
  const float* sWk   = (const float*)d_in[25];
  const float* sWv   = (const float*)d_in[26];
  const float* sbq   = (const float*)d_in[27];
  const float* sbk   = (const float*)d_in[28];
  const float* sbv   = (const float*)d_in[29];
  const float* sWo   = (const float*)d_in[30];
  const float* sbo   = (const float*)d_in[31];
  const float* n3_g  = (const float*)d_in[32];
  const float* n3_b  = (const float*)d_in[33];
  const float* Wc    = (const float*)d_in[34];
  const float* bc    = (const float*)d_in[35];

  const int Bn = 16384;
  constexpr size_t SZ_BIG = (size_t)16384 * 2048 * 2;   // 64 MiB
  constexpr size_t SZ_ACT = (size_t)16384 * 1024 * 2;   // 32 MiB
  constexpr size_t OFF_S = 0;
  constexpr size_t OFF_A = OFF_S + SZ_BIG;
  constexpr size_t OFF_B = OFF_A + SZ_ACT;   // == 96 MiB
  constexpr size_t OFF_C = OFF_B + SZ_ACT;
  constexpr size_t OFF_D = OFF_C + SZ_ACT;
  constexpr size_t OFF_E = OFF_D + SZ_ACT;
  constexpr size_t OFF_F = OFF_E + SZ_ACT;
  constexpr size_t OFF_W = OFF_F + SZ_ACT;

  uint8_t* ws = (uint8_t*)d_ws;
  u16* S_b  = (u16*)(ws + OFF_S);   // spatial bf16 (later Gb; later qkv[0:96MB))
  u16* F_b  = (u16*)(ws + OFF_A);   // freq bf16
  u16* Qb   = (u16*)(ws + OFF_B);   // (later Hb)
  u16* KVb  = (u16*)(ws + OFF_C);   // live until kv1 GEMM; then Ob
  u16* Vb   = (u16*)(ws + OFF_D);   // (later X2b)
  u16* AOb  = (u16*)(ws + OFF_E);   // (later kv1[0:64MB))
  u16* X1b  = (u16*)(ws + OFF_F);

  u16* wWps = (u16*)(ws + OFF_W);
  u16* wWpf = wWps + (size_t)1024 * 2048;
  u16* wWv  = wWpf + (size_t)1024 * 1024;
  u16* wWo  = wWv  + (size_t)1024 * 1024;
  u16* wW1  = wWo  + (size_t)1024 * 1024;
  u16* wW2  = wW1  + (size_t)2048 * 1024;
  u16* wSq  = wW2  + (size_t)1024 * 2048;   // wSq|wSk|wSv contiguous -> batched N=3072 GEMM
  u16* wSk  = wSq  + (size_t)1024 * 1024;
  u16* wSv  = wSk  + (size_t)1024 * 1024;
  u16* wSo  = wSv  + (size_t)1024 * 1024;
  float* bQKV = (float*)(wSo + (size_t)1024 * 1024);  // 3072 f32: sbq|sbk|sbv
  float* bKV  = bQKV + 3072;                          // 2048 f32: sbk|sbv

  // aliases (phase-based reuse)
  u16* Gb  = (u16*)(ws + OFF_S);
  u16* Hb  = (u16*)(ws + OFF_B);
  u16* X2b = (u16*)(ws + OFF_D);
  u16* qkv = (u16*)(ws + OFF_S);             // [16384][3072] : q0|k0|v0
  u16* kv1 = (u16*)(ws + OFF_E);             // [16384][2048] : k1|v1
  u16* Ob  = (u16*)(ws + OFF_C);
  u16* POb = (u16*)(ws + OFF_S);             // qkv region free after attn2

  auto cvt = [&](const float* src, u16* dst, size_t n) {
    int n4 = (int)(n >> 2);
    cvt_kernel<<<dim3((n4 + 255) / 256), dim3(256), 0, stream>>>(src, dst, n4);
  };
  auto gemm = [&](const u16* A_, const u16* W_, const float* bias, const float* bias2,
                  u16* C_, int N, int K, bool gelu) {
    const int nTn = N >> 8;
    dim3 grid(64 * nTn);   // (16384/256) * (N/256); always % 8 == 0
    if (gelu) gemm256<1><<<grid, dim3(512), 0, stream>>>(A_, W_, bias, bias2, C_, N, K, nTn);
    else      gemm256<0><<<grid, dim3(512), 0, stream>>>(A_, W_, bias, bias2, C_, N, K, nTn);
  };

  // 0) convert inputs + weights to bf16; concat self-attn biases (d2d, capture-safe)
  cvt(spatial, S_b, (size_t)Bn * 2048);
  cvt(freq,    F_b, (size_t)Bn * 1024);
  cvt(Wps, wWps, (size_t)1024 * 2048);
  cvt(Wpf, wWpf, (size_t)1024 * 1024);
  cvt(ca_Wv, wWv, (size_t)1024 * 1024);
  cvt(ca_Wo, wWo, (size_t)1024 * 1024);
  cvt(W1, wW1, (size_t)2048 * 1024);
  cvt(W2, wW2, (size_t)1024 * 2048);
  cvt(sWq, wSq, (size_t)1024 * 1024);
  cvt(sWk, wSk, (size_t)1024 * 1024);
  cvt(sWv, wSv, (size_t)1024 * 1024);
  cvt(sWo, wSo, (size_t)1024 * 1024);
  hipMemcpyAsync(bQKV,        sbq, 1024 * sizeof(float), hipMemcpyDeviceToDevice, stream);
  hipMemcpyAsync(bQKV + 1024, sbk, 1024 * sizeof(float), hipMemcpyDeviceToDevice, stream);
  hipMemcpyAsync(bQKV + 2048, sbv, 1024 * sizeof(float), hipMemcpyDeviceToDevice, stream);
  hipMemcpyAsync(bKV,         sbk, 1024 * sizeof(float), hipMemcpyDeviceToDevice, stream);
  hipMemcpyAsync(bKV + 1024,  sbv, 1024 * sizeof(float), hipMemcpyDeviceToDevice, stream);

  // 1) Q = spatial @ Wps^T + bps + pos_s
  gemm(S_b, wWps, bps, pos_s, Qb, 1024, 2048, false);
  // 2) KV = freq @ Wpf^T + bpf + pos_f
  gemm(F_b, wWpf, bpf, pos_f, KVb, 1024, 1024, false);
  // 3) V = KV @ ca_Wv^T + ca_bv ; 4) AO = V @ ca_Wo^T + ca_bo  (cross-attn collapsed)
  gemm(KVb, wWv, ca_bv, nullptr, Vb, 1024, 1024, false);
  gemm(Vb, wWo, ca_bo, nullptr, AOb, 1024, 1024, false);
  // 5) X1 = LN(Q + AO)
  ln_res<<<dim3(Bn), dim3(256), 0, stream>>>(Qb, AOb, n1_g, n1_b, X1b);
  // 6) G = gelu(X1 @ W1^T + b1) ; 7) H = G @ W2^T + b2
  gemm(X1b, wW1, b1, nullptr, Gb, 2048, 1024, true);
  gemm(Gb, wW2, b2, nullptr, Hb, 1024, 2048, false);
  // 8) X2 = LN(X1 + H)
  ln_res<<<dim3(Bn), dim3(256), 0, stream>>>(X1b, Hb, n2_g, n2_b, X2b);
  // 9) [q0|k0|v0] = X2 @ [Wq|Wk|Wv]^T  (batched, N=3072)
  gemm(X2b, wSq, bQKV, nullptr, qkv, 3072, 1024, false);
  // 10) [k1|v1] = KV @ [Wk|Wv]^T  (batched, N=2048)
  gemm(KVb, wSk, bKV, nullptr, kv1, 2048, 1024, false);
  // 11) 2-key attention combine per head
  attn2<<<dim3(Bn), dim3(256), 0, stream>>>(qkv, qkv + 1024, qkv + 2048, 3072,
                                            kv1, kv1 + 1024, 2048, Ob);
  // 12) PO = O @ sa_Wo^T + sa_bo
  gemm(Ob, wSo, sbo, nullptr, POb, 1024, 1024, false);
  // 13) out = LN(X2 + PO; n3) . Wc + bc
  final_k<<<dim3(Bn), dim3(256), 0, stream>>>(X2b, POb, n3_g, n3_b, Wc, bc, (float*)d_out);
}

// Round 6
// 756.163 us; speedup vs baseline: 1.0101x; 1.0101x over previous
//
#include <hip/hip_runtime.h>
#include <hip/hip_bf16.h>
#include <cstdint>
#include <cstddef>

typedef unsigned short u16;
typedef __bf16 bf16x8 __attribute__((ext_vector_type(8)));
typedef float f32x4 __attribute__((ext_vector_type(4)));

#define GLOBAL_AS(p) ((const __attribute__((address_space(1))) void*)(p))
#define LDS_AS(p)    ((__attribute__((address_space(3))) void*)(p))

__device__ __forceinline__ float b2f(u16 u) {
  return __builtin_bit_cast(float, (unsigned)u << 16);
}
__device__ __forceinline__ u16 f2b(float f) {
  unsigned u = __builtin_bit_cast(unsigned, f);
  u += 0x7FFFu + ((u >> 16) & 1u);   // round-to-nearest-even
  return (u16)(u >> 16);
}

// ---------------- f32 -> bf16 convert (4 elems/thread) ----------------
__global__ __launch_bounds__(256) void cvt_kernel(const float* __restrict__ src,
                                                  u16* __restrict__ dst, int n4) {
  int i = blockIdx.x * 256 + threadIdx.x;
  if (i < n4) {
    float4 f = ((const float4*)src)[i];
    ushort4 o;
    o.x = f2b(f.x); o.y = f2b(f.y); o.z = f2b(f.z); o.w = f2b(f.w);
    ((ushort4*)dst)[i] = o;
  }
}

// ---------------- merged weight convert: 10 segments -> one contiguous dst ----------------
struct CvtArgs {
  const float* src[10];
  unsigned cum[11];   // cumulative float4 counts
};
__global__ __launch_bounds__(256) void cvt_multi(CvtArgs a, u16* __restrict__ dst) {
  unsigned i = blockIdx.x * 256 + threadIdx.x;
  if (i >= a.cum[10]) return;
  int k = 0;
#pragma unroll
  for (int j = 1; j < 10; ++j) if (i >= a.cum[j]) k = j;
  float4 f = ((const float4*)a.src[k])[i - a.cum[k]];
  ushort4 o;
  o.x = f2b(f.x); o.y = f2b(f.y); o.z = f2b(f.z); o.w = f2b(f.w);
  ((ushort4*)dst)[i] = o;
}

// ---------------- 256x256 GEMM, BK=32, 8 waves; 4-buffer LDS ring, depth-3 prefetch ----
// C(bf16, MxN) = A(bf16, MxK) @ W(bf16, NxK)^T + bias [+bias2] [gelu]
// LDS ring: 4 buffers x (A [256][32] + B [256][32]) bf16 = 4 x 32 KiB = 128 KiB.
// Per K-tile: issue STAGE(kt+3) (4 DMA/thread), 12 ds_read_b128, 32 MFMA, then
// counted vmcnt(8) (drains ONLY tile kt+1; kt+2/kt+3 stay in flight) + raw s_barrier.
// WAR: buf[(kt+3)&3] last read in tile kt-1, lgkm-retired before its barrier; STG after.
// RAW: vmcnt(8) at boundary kt guarantees tile kt+1's 4 loads landed.
// Swizzle (T2, rule #21): stored c4 = c4 ^ ((row>>1)&3); DMA dest linear, per-lane
// global SOURCE pre-swizzled (involution), ds_read applies same XOR -> 2-way (free).
template<int EPI>  // 0 = none, 1 = exact gelu
__global__ __launch_bounds__(512, 2)
void gemm256(const u16* __restrict__ A, const u16* __restrict__ W,
             const float* __restrict__ bias, const float* __restrict__ bias2,
             u16* __restrict__ C, int N, int K, int nTn)
{
  __shared__ alignas(16) u16 LDS[69632];   // ring 128 KiB + epilogue overlay headroom
  const int tid  = threadIdx.x;
  const int lane = tid & 63;
  const int wave = tid >> 6;

  // T1: XCD-chunked bijective swizzle (gridDim.x % 8 == 0 for all our shapes)
  const int bqc = (int)gridDim.x >> 3;
  const int t  = ((int)blockIdx.x & 7) * bqc + ((int)blockIdx.x >> 3);
  const int bm = t / nTn, bn = t % nTn;
  const size_t row0 = (size_t)bm << 8;
  const int col0 = bn << 8;

  // ---- staging geometry: plane [256][32] u16 = 16 KiB = 2 DMA rounds (8 KiB each).
  // round j: wave w, lane l -> dest u16 off = j*4096 + w*512 + l*8  (HW: base + lane*16B)
  //   => row = j*128 + w*16 + (l>>2), stored c4 = l&3.
  // source col pre-swizzled: src_c4 = (l&3) ^ ((l>>3)&3)   [(row>>1)&3 == (l>>3)&3]
  const int sr  = (wave << 4) + (lane >> 2);
  const int c4s = ((lane & 3) ^ ((lane >> 3) & 3)) << 3;
  const u16* gA = A + ((size_t)row0 + sr) * K + c4s;
  const u16* gB = W + ((size_t)col0 + sr) * K + c4s;
  const size_t rK = (size_t)128 * K;
  const int stW = wave << 9;               // wave*512 u16, wave-uniform dest offset

  // ---- fragment read geometry
  const int wm = wave >> 2, wn = wave & 3;
  const int fr = lane & 15, kq = lane >> 4;
  const int c4r = (kq ^ ((fr >> 1) & 3)) << 3;         // swizzled 16B block (u16 elems)
  const int aBase = (wm * 128 + fr) * 32 + c4r;        // within A plane
  const int bBase = (wn * 64 + fr) * 32 + c4r;         // within B plane

  auto STG = [&](int kt, int buf) {
    const int koff = kt << 5;
    u16* dA = LDS + buf * 16384 + stW;
    u16* dB = dA + 8192;
    __builtin_amdgcn_global_load_lds(GLOBAL_AS(gA + koff),      LDS_AS(dA),        16, 0, 0);
    __builtin_amdgcn_global_load_lds(GLOBAL_AS(gA + rK + koff), LDS_AS(dA + 4096), 16, 0, 0);
    __builtin_amdgcn_global_load_lds(GLOBAL_AS(gB + koff),      LDS_AS(dB),        16, 0, 0);
    __builtin_amdgcn_global_load_lds(GLOBAL_AS(gB + rK + koff), LDS_AS(dB + 4096), 16, 0, 0);
  };

  f32x4 acc[8][4];
  {
    f32x4 z = {0.f, 0.f, 0.f, 0.f};
#pragma unroll
    for (int m = 0; m < 8; ++m)
#pragma unroll
      for (int n = 0; n < 4; ++n) acc[m][n] = z;
  }

  const int NT = K >> 5;   // >= 32 for all our shapes

  // prologue: stage tiles 0,1,2 (12 loads); drain tile 0 only
  STG(0, 0);
  STG(1, 1);
  STG(2, 2);
  asm volatile("s_waitcnt vmcnt(8)" ::: "memory");
  __builtin_amdgcn_s_barrier();

  for (int kt = 0; kt < NT; ++kt) {
    const int buf = kt & 3;
    if (kt + 3 < NT) STG(kt + 3, (kt + 3) & 3);   // depth-3 prefetch

    const u16* La = LDS + buf * 16384;
    const u16* Lb = La + 8192;
    bf16x8 af[8], bv[4];
#pragma unroll
    for (int m = 0; m < 8; ++m) af[m] = *(const bf16x8*)(La + aBase + m * 512);
#pragma unroll
    for (int n = 0; n < 4; ++n) bv[n] = *(const bf16x8*)(Lb + bBase + n * 512);

    __builtin_amdgcn_s_setprio(1);
#pragma unroll
    for (int m = 0; m < 8; ++m)
#pragma unroll
      for (int n = 0; n < 4; ++n)
        acc[m][n] = __builtin_amdgcn_mfma_f32_16x16x32_bf16(af[m], bv[n], acc[m][n], 0, 0, 0);
    __builtin_amdgcn_s_setprio(0);

    // counted boundary wait: drain only tile kt+1 (tail: fewer outstanding)
    if (kt + 3 < NT)      asm volatile("s_waitcnt vmcnt(8)" ::: "memory");
    else if (kt + 2 < NT) asm volatile("s_waitcnt vmcnt(4)" ::: "memory");
    else                  asm volatile("s_waitcnt vmcnt(0)" ::: "memory");
    __builtin_amdgcn_s_barrier();
  }

  // ---- epilogue: wave-private LDS transpose -> coalesced 16B stores ----
  u16* Wl = LDS + wave * 8704;                 // 128 x 68 u16 (pad breaks kq-bank overlap)
  const int orow = kq << 2;
#pragma unroll
  for (int n = 0; n < 4; ++n) {
    const int gcol = col0 + wn * 64 + n * 16 + fr;
    float bb = 0.f;
    if (bias)  bb += bias[gcol];
    if (bias2) bb += bias2[gcol];
#pragma unroll
    for (int m = 0; m < 8; ++m) {
#pragma unroll
      for (int r = 0; r < 4; ++r) {
        float v = acc[m][n][r] + bb;
        if (EPI == 1) v = 0.5f * v * (1.f + erff(v * 0.70710678118654752f));
        Wl[(m * 16 + orow + r) * 68 + n * 16 + fr] = f2b(v);
      }
    }
  }
  asm volatile("s_waitcnt lgkmcnt(0)" ::: "memory");   // wave-private: no barrier needed
#pragma unroll
  for (int p = 0; p < 16; ++p) {
    const int row = p * 8 + (lane >> 3);
    const int cu  = (lane & 7) << 3;
    bf16x8 v = *(const bf16x8*)(Wl + row * 68 + cu);
    *(bf16x8*)(&C[(row0 + wm * 128 + row) * N + col0 + wn * 64 + cu]) = v;
  }
}

// ---------------- LayerNorm of residual sum: O = LN(X + Y) * g + b, row width 1024 ----
__global__ __launch_bounds__(256)
void ln_res(const u16* __restrict__ X, const u16* __restrict__ Y,
            const float* __restrict__ g, const float* __restrict__ bta,
            u16* __restrict__ O)
{
  const int row = blockIdx.x;
  const int tid = threadIdx.x;
  const size_t base = (size_t)row * 1024 + tid * 4;
  ushort4 xv = *(const ushort4*)(X + base);
  ushort4 yv = *(const ushort4*)(Y + base);
  float v0 = b2f(xv.x) + b2f(yv.x);
  float v1 = b2f(xv.y) + b2f(yv.y);
  float v2 = b2f(xv.z) + b2f(yv.z);
  float v3 = b2f(xv.w) + b2f(yv.w);
  float s  = v0 + v1 + v2 + v3;
  float ss = v0*v0 + v1*v1 + v2*v2 + v3*v3;
#pragma unroll
  for (int off = 32; off; off >>= 1) {
    s  += __shfl_down(s, off);
    ss += __shfl_down(ss, off);
  }
  __shared__ float red[8];
  if ((tid & 63) == 0) { red[tid >> 6] = s; red[4 + (tid >> 6)] = ss; }
  __syncthreads();
  const float S  = red[0] + red[1] + red[2] + red[3];
  const float SS = red[4] + red[5] + red[6] + red[7];
  const float mu  = S * (1.f / 1024.f);
  const float inv = rsqrtf(SS * (1.f / 1024.f) - mu * mu + 1e-5f);
  const int n = tid * 4;
  float4 gv = *(const float4*)(g + n);
  float4 bv = *(const float4*)(bta + n);
  ushort4 o;
  o.x = f2b((v0 - mu) * inv * gv.x + bv.x);
  o.y = f2b((v1 - mu) * inv * gv.y + bv.y);
  o.z = f2b((v2 - mu) * inv * gv.z + bv.z);
  o.w = f2b((v3 - mu) * inv * gv.w + bv.w);
  *(ushort4*)(O + base) = o;
}

// ---------------- 2-key attention combine, 8 heads of d=128 (strided inputs) ----------------
__global__ __launch_bounds__(256)
void attn2(const u16* __restrict__ Q, const u16* __restrict__ K0, const u16* __restrict__ V0, int sQ,
           const u16* __restrict__ K1, const u16* __restrict__ V1, int sK,
           u16* __restrict__ O)
{
  const int row = blockIdx.x;
  const int tid = threadIdx.x;
  const size_t bq = (size_t)row * sQ + tid * 4;
  const size_t bk = (size_t)row * sK + tid * 4;
  const size_t bo = (size_t)row * 1024 + tid * 4;
  ushort4 qv  = *(const ushort4*)(Q  + bq);
  ushort4 k0v = *(const ushort4*)(K0 + bq);
  ushort4 v0v = *(const ushort4*)(V0 + bq);
  ushort4 k1v = *(const ushort4*)(K1 + bk);
  ushort4 v1v = *(const ushort4*)(V1 + bk);
  float q0 = b2f(qv.x), q1 = b2f(qv.y), q2 = b2f(qv.z), q3 = b2f(qv.w);
  float d0 = q0*b2f(k0v.x) + q1*b2f(k0v.y) + q2*b2f(k0v.z) + q3*b2f(k0v.w);
  float d1 = q0*b2f(k1v.x) + q1*b2f(k1v.y) + q2*b2f(k1v.z) + q3*b2f(k1v.w);
#pragma unroll
  for (int off = 16; off; off >>= 1) {
    d0 += __shfl_xor(d0, off);
    d1 += __shfl_xor(d1, off);
  }
  const float sc = 0.088388347648318447f;  // 1/sqrt(128)
  float s0 = d0 * sc, s1 = d1 * sc;
  float mx = fmaxf(s0, s1);
  float e0 = expf(s0 - mx), e1 = expf(s1 - mx);
  float r = 1.f / (e0 + e1);
  float a0 = e0 * r, a1 = e1 * r;
  ushort4 o;
  o.x = f2b(a0 * b2f(v0v.x) + a1 * b2f(v1v.x));
  o.y = f2b(a0 * b2f(v0v.y) + a1 * b2f(v1v.y));
  o.z = f2b(a0 * b2f(v0v.z) + a1 * b2f(v1v.z));
  o.w = f2b(a0 * b2f(v0v.w) + a1 * b2f(v1v.w));
  *(ushort4*)(O + bo) = o;
}

// ---------------- final: out[row] = dot(LN(X + Y)*g + b, Wc) + bc ----------------
__global__ __launch_bounds__(256)
void final_k(const u16* __restrict__ X, const u16* __restrict__ Y,
             const float* __restrict__ g, const float* __restrict__ bta,
             const float* __restrict__ Wc, const float* __restrict__ bc,
             float* __restrict__ out)
{
  const int row = blockIdx.x;
  const int tid = threadIdx.x;
  const size_t base = (size_t)row * 1024 + tid * 4;
  ushort4 xv = *(const ushort4*)(X + base);
  ushort4 yv = *(const ushort4*)(Y + base);
  float v0 = b2f(xv.x) + b2f(yv.x);
  float v1 = b2f(xv.y) + b2f(yv.y);
  float v2 = b2f(xv.z) + b2f(yv.z);
  float v3 = b2f(xv.w) + b2f(yv.w);
  float s  = v0 + v1 + v2 + v3;
  float ss = v0*v0 + v1*v1 + v2*v2 + v3*v3;
#pragma unroll
  for (int off = 32; off; off >>= 1) {
    s  += __shfl_down(s, off);
    ss += __shfl_down(ss, off);
  }
  __shared__ float red[8];
  __shared__ float red2[4];
  if ((tid & 63) == 0) { red[tid >> 6] = s; red[4 + (tid >> 6)] = ss; }
  __syncthreads();
  const float S  = red[0] + red[1] + red[2] + red[3];
  const float SS = red[4] + red[5] + red[6] + red[7];
  const float mu  = S * (1.f / 1024.f);
  const float inv = rsqrtf(SS * (1.f / 1024.f) - mu * mu + 1e-5f);
  const int n = tid * 4;
  float4 gv = *(const float4*)(g + n);
  float4 bv = *(const float4*)(bta + n);
  float4 wv = *(const float4*)(Wc + n);
  float dot = ((v0 - mu) * inv * gv.x + bv.x) * wv.x
            + ((v1 - mu) * inv * gv.y + bv.y) * wv.y
            + ((v2 - mu) * inv * gv.z + bv.z) * wv.z
            + ((v3 - mu) * inv * gv.w + bv.w) * wv.w;
#pragma unroll
  for (int off = 32; off; off >>= 1) dot += __shfl_down(dot, off);
  if ((tid & 63) == 0) red2[tid >> 6] = dot;
  __syncthreads();
  if (tid == 0) out[row] = red2[0] + red2[1] + red2[2] + red2[3] + bc[0];
}

// =====================================================================
extern "C" void kernel_launch(void* const* d_in, const int* in_sizes, int n_in,
                              void* d_out, int out_size, void* d_ws, size_t ws_size,
                              hipStream_t stream) {
  const float* spatial = (const float*)d_in[0];
  const float* freq    = (const float*)d_in[1];
  const float* Wps   = (const float*)d_in[2];
  const float* bps   = (const float*)d_in[3];
  const float* Wpf   = (const float*)d_in[4];
  const float* bpf   = (const float*)d_in[5];
  // d_in[8], d_in[9], d_in[11], d_in[12] (ca_Wq/ca_Wk/ca_bq/ca_bk) are dead: softmax over 1 key == 1
  const float* pos_s = (const float*)d_in[6];
  const float* pos_f = (const float*)d_in[7];
  const float* ca_Wv = (const float*)d_in[10];
  const float* ca_bv = (const float*)d_in[13];
  const float* ca_Wo = (const float*)d_in[14];
  const float* ca_bo = (const float*)d_in[15];
  const float* n1_g  = (const float*)d_in[16];
  const float* n1_b  = (const float*)d_in[17];
  const float* W1    = (const float*)d_in[18];
  const float* b1    = (const float*)d_in[19];
  const float* W2    = (const float*)d_in[20];
  const float* b2    = (const float*)d_in[21];
  const float* n2_g  = (const float*)d_in[22];
  const float* n2_b  = (const float*)d_in[23];
  const float* sWq   = (const float*)d_in[24];
  const float* sWk   = (const float*)d_in[25];
  const float* sWv   = (const float*)d_in[26];
  const float* sbq   = (const float*)d_in[27];
  const float* sbk   = (const float*)d_in[28];
  const float* sbv   = (const float*)d_in[29];
  const float* sWo   = (const float*)d_in[30];
  const float* sbo   = (const float*)d_in[31];
  const float* n3_g  = (const float*)d_in[32];
  const float* n3_b  = (const float*)d_in[33];
  const float* Wc    = (const float*)d_in[34];
  const float* bc    = (const float*)d_in[35];

  const int Bn = 16384;
  constexpr size_t SZ_BIG = (size_t)16384 * 2048 * 2;   // 64 MiB
  constexpr size_t SZ_ACT = (size_t)16384 * 1024 * 2;   // 32 MiB
  constexpr size_t OFF_S = 0;
  constexpr size_t OFF_A = OFF_S + SZ_BIG;
  constexpr size_t OFF_B = OFF_A + SZ_ACT;   // == 96 MiB
  constexpr size_t OFF_C = OFF_B + SZ_ACT;
  constexpr size_t OFF_D = OFF_C + SZ_ACT;
  constexpr size_t OFF_E = OFF_D + SZ_ACT;
  constexpr size_t OFF_F = OFF_E + SZ_ACT;
  constexpr size_t OFF_W = OFF_F + SZ_ACT;

  uint8_t* ws = (uint8_t*)d_ws;
  u16* S_b  = (u16*)(ws + OFF_S);   // spatial bf16 (later Gb; later qkv[0:96MB))
  u16* F_b  = (u16*)(ws + OFF_A);   // freq bf16
  u16* Qb   = (u16*)(ws + OFF_B);   // (later Hb)
  u16* KVb  = (u16*)(ws + OFF_C);   // live until kv1 GEMM; then Ob
  u16* Vb   = (u16*)(ws + OFF_D);   // (later X2b)
  u16* AOb  = (u16*)(ws + OFF_E);   // (later kv1[0:64MB))
  u16* X1b  = (u16*)(ws + OFF_F);

  u16* wWps = (u16*)(ws + OFF_W);   // weight region: 10 contiguous segments
  u16* wWpf = wWps + (size_t)1024 * 2048;
  u16* wWv  = wWpf + (size_t)1024 * 1024;
  u16* wWo  = wWv  + (size_t)1024 * 1024;
  u16* wW1  = wWo  + (size_t)1024 * 1024;
  u16* wW2  = wW1  + (size_t)2048 * 1024;
  u16* wSq  = wW2  + (size_t)1024 * 2048;   // wSq|wSk|wSv contiguous -> batched N=3072 GEMM
  u16* wSk  = wSq  + (size_t)1024 * 1024;
  u16* wSv  = wSk  + (size_t)1024 * 1024;
  u16* wSo  = wSv  + (size_t)1024 * 1024;
  float* bQKV = (float*)(wSo + (size_t)1024 * 1024);  // 3072 f32: sbq|sbk|sbv
  float* bKV  = bQKV + 3072;                          // 2048 f32: sbk|sbv

  // aliases (phase-based reuse)
  u16* Gb  = (u16*)(ws + OFF_S);
  u16* Hb  = (u16*)(ws + OFF_B);
  u16* X2b = (u16*)(ws + OFF_D);
  u16* qkv = (u16*)(ws + OFF_S);             // [16384][3072] : q0|k0|v0
  u16* kv1 = (u16*)(ws + OFF_E);             // [16384][2048] : k1|v1
  u16* Ob  = (u16*)(ws + OFF_C);
  u16* POb = (u16*)(ws + OFF_S);             // qkv region free after attn2

  auto cvt = [&](const float* src, u16* dst, size_t n) {
    int n4 = (int)(n >> 2);
    cvt_kernel<<<dim3((n4 + 255) / 256), dim3(256), 0, stream>>>(src, dst, n4);
  };
  auto gemm = [&](const u16* A_, const u16* W_, const float* bias, const float* bias2,
                  u16* C_, int N, int K, bool gelu) {
    const int nTn = N >> 8;
    dim3 grid(64 * nTn);   // (16384/256) * (N/256); always % 8 == 0
    if (gelu) gemm256<1><<<grid, dim3(512), 0, stream>>>(A_, W_, bias, bias2, C_, N, K, nTn);
    else      gemm256<0><<<grid, dim3(512), 0, stream>>>(A_, W_, bias, bias2, C_, N, K, nTn);
  };

  // 0) convert inputs to bf16; all 10 weights in ONE merged kernel (contiguous dst)
  cvt(spatial, S_b, (size_t)Bn * 2048);
  cvt(freq,    F_b, (size_t)Bn * 1024);
  {
    CvtArgs a;
    const float* srcs[10] = {Wps, Wpf, ca_Wv, ca_Wo, W1, W2, sWq, sWk, sWv, sWo};
    const unsigned segs[10] = {524288, 262144, 262144, 262144, 524288, 524288,
                               262144, 262144, 262144, 262144};  // float4 counts
    unsigned c = 0;
    for (int i = 0; i < 10; ++i) { a.src[i] = srcs[i]; a.cum[i] = c; c += segs[i]; }
    a.cum[10] = c;
    cvt_multi<<<dim3((c + 255) / 256), dim3(256), 0, stream>>>(a, wWps);
  }
  hipMemcpyAsync(bQKV,        sbq, 1024 * sizeof(float), hipMemcpyDeviceToDevice, stream);
  hipMemcpyAsync(bQKV + 1024, sbk, 1024 * sizeof(float), hipMemcpyDeviceToDevice, stream);
  hipMemcpyAsync(bQKV + 2048, sbv, 1024 * sizeof(float), hipMemcpyDeviceToDevice, stream);
  hipMemcpyAsync(bKV,         sbk, 1024 * sizeof(float), hipMemcpyDeviceToDevice, stream);
  hipMemcpyAsync(bKV + 1024,  sbv, 1024 * sizeof(float), hipMemcpyDeviceToDevice, stream);

  // 1) Q = spatial @ Wps^T + bps + pos_s
  gemm(S_b, wWps, bps, pos_s, Qb, 1024, 2048, false);
  // 2) KV = freq @ Wpf^T + bpf + pos_f
  gemm(F_b, wWpf, bpf, pos_f, KVb, 1024, 1024, false);
  // 3) V = KV @ ca_Wv^T + ca_bv ; 4) AO = V @ ca_Wo^T + ca_bo  (cross-attn collapsed)
  gemm(KVb, wWv, ca_bv, nullptr, Vb, 1024, 1024, false);
  gemm(Vb, wWo, ca_bo, nullptr, AOb, 1024, 1024, false);
  // 5) X1 = LN(Q + AO)
  ln_res<<<dim3(Bn), dim3(256), 0, stream>>>(Qb, AOb, n1_g, n1_b, X1b);
  // 6) G = gelu(X1 @ W1^T + b1) ; 7) H = G @ W2^T + b2
  gemm(X1b, wW1, b1, nullptr, Gb, 2048, 1024, true);
  gemm(Gb, wW2, b2, nullptr, Hb, 1024, 2048, false);
  // 8) X2 = LN(X1 + H)
  ln_res<<<dim3(Bn), dim3(256), 0, stream>>>(X1b, Hb, n2_g, n2_b, X2b);
  // 9) [q0|k0|v0] = X2 @ [Wq|Wk|Wv]^T  (batched, N=3072)
  gemm(X2b, wSq, bQKV, nullptr, qkv, 3072, 1024, false);
  // 10) [k1|v1] = KV @ [Wk|Wv]^T  (batched, N=2048)
  gemm(KVb, wSk, bKV, nullptr, kv1, 2048, 1024, false);
  // 11) 2-key attention combine per head
  attn2<<<dim3(Bn), dim3(256), 0, stream>>>(qkv, qkv + 1024, qkv + 2048, 3072,
                                            kv1, kv1 + 1024, 2048, Ob);
  // 12) PO = O @ sa_Wo^T + sa_bo
  gemm(Ob, wSo, sbo, nullptr, POb, 1024, 1024, false);
  // 13) out = LN(X2 + PO; n3) . Wc + bc
  final_k<<<dim3(Bn), dim3(256), 0, stream>>>(X2b, POb, n3_g, n3_b, Wc, bc, (float*)d_out);
}